// Round 1
// baseline (2605.780 us; speedup 1.0000x reference)
//
#include <hip/hip_runtime.h>

// Inputs: fp32. Outputs: fp32 (established round 3: PASSED).

constexpr int BB = 4;
constexpr int NN = 4096;
constexpr int M1 = 2048;
constexpr int M2 = 512;

// Exact fp32 squared distance matching numpy's (dx*dx) + (dy*dy), no fma contraction.
__device__ __forceinline__ float d2_exact(float dx, float dy) {
    return __fadd_rn(__fmul_rn(dx, dx), __fmul_rn(dy, dy));
}

// DPP with bound_ctrl=1 (invalid source lanes read 0 — zero key always loses
// since real keys > 0). Proven ctrl sequence: 0x111/0x112/0x114/0x118 are
// row_shr 1/2/4/8 (lane i <- lane i-N within 16-lane row, result at lanes
// 15/31/47/63), 0x142/0x143 row_bcast15/31 -> total at lane 63.
template<int CTRL>
__device__ __forceinline__ unsigned long long dpp64z(unsigned long long v) {
    unsigned lo = (unsigned)__builtin_amdgcn_update_dpp(0, (int)(unsigned)v, CTRL, 0xF, 0xF, true);
    unsigned hi = (unsigned)__builtin_amdgcn_update_dpp(0, (int)(unsigned)(v >> 32), CTRL, 0xF, 0xF, true);
    return ((unsigned long long)hi << 32) | (unsigned long long)lo;
}
template<int CTRL>
__device__ __forceinline__ float dppfz(float v) {
    return __uint_as_float((unsigned)__builtin_amdgcn_update_dpp(
        0, (int)__float_as_uint(v), CTRL, 0xF, 0xF, true));
}
// Keyed max with (x,y) payload riding the same select. Bit-preserving moves only.
template<int CTRL>
__device__ __forceinline__ void max1p(unsigned long long& k, float& x, float& y) {
    unsigned long long ok = dpp64z<CTRL>(k);
    float ox = dppfz<CTRL>(x);
    float oy = dppfz<CTRL>(y);
    bool g = ok > k;
    k = g ? ok : k;
    x = g ? ox : x;
    y = g ? oy : y;
}

// ---------------------------------------------------------------------------
// lf = tanh(tanh(x@W1+b1)@W2+b2) -> out (fp32); also
// y1[j,f] = lf_j@c1W[0:64] + zones_j*c1W[64] + pos_j@c1W[65:67] + c1b (fp32 ws)
// ---------------------------------------------------------------------------
__global__ __launch_bounds__(256) void k_lf_y1(
    const float2* __restrict__ x, const float* __restrict__ zones,
    const float* __restrict__ W1, const float* __restrict__ b1,
    const float* __restrict__ W2, const float* __restrict__ b2,
    const float* __restrict__ c1W, const float* __restrict__ c1b,
    float* __restrict__ out_lf, float* __restrict__ y1)
{
    __shared__ float sh[4][64];
    __shared__ float sl[4][64];
    int tid = threadIdx.x;
    int p = tid >> 6, f = tid & 63;
    size_t pt = (size_t)blockIdx.x * 4 + p;
    float2 xv = x[pt];
    float hid = tanhf(xv.x * W1[f] + xv.y * W1[64 + f] + b1[f]);
    sh[p][f] = hid;
    __syncthreads();
    float acc = b2[f];
#pragma unroll
    for (int c = 0; c < 64; ++c) acc += sh[p][c] * W2[c * 64 + f];
    float lf = tanhf(acc);
    sl[p][f] = lf;
    out_lf[pt * 64 + f] = lf;
    __syncthreads();
    float acc2 = c1b[f] + zones[pt] * c1W[64 * 64 + f]
               + xv.x * c1W[65 * 64 + f] + xv.y * c1W[66 * 64 + f];
#pragma unroll
    for (int c = 0; c < 64; ++c) acc2 += sl[p][c] * c1W[c * 64 + f];
    y1[pt * 64 + f] = acc2;
}

// ---------------------------------------------------------------------------
// Lazy chunked FPS.
//
// Invariants (bit-exactness vs reference scan):
//  * md[p] = min over picked centers c of d2_exact(p - c); min is
//    order-independent, so any update order / any skipped no-op update
//    yields identical bits.
//  * Skip rule: for chunk with bbox B and cached max-md m, if
//    boxd2(B, c) >= m then for every p in chunk d2(p,c) >= boxd2 >= m >= md[p]
//    (boxd2 built from rn-monotone sub/mul/add => boxd2 <= d2(p,c) exactly),
//    so the chunk's md values AND its cached best key are unchanged.
//  * argmax with FIRST-index tie-break via unique u64 key
//    = bits(md)<<32 | (0xFFFFFFFF - original_index).
//  * Winner's chunk is always affected next round (boxd2 = 0 < max-md),
//    so md[winner] -> 0 exactly as in the reference.
//  * Chunk partition (atomics order in counting sort) cannot change results:
//    global max over chunk-maxes = max over all points regardless of split.
// ---------------------------------------------------------------------------

__device__ __forceinline__ unsigned part1by1(unsigned v) {
    v = (v | (v << 8)) & 0x00FF00FFu;
    v = (v | (v << 4)) & 0x0F0F0F0Fu;
    v = (v | (v << 2)) & 0x33333333u;
    v = (v | (v << 1)) & 0x55555555u;
    return v;
}
__device__ __forceinline__ unsigned mortcid(float px, float py, float lx, float ly,
                                            float sx, float sy) {
    int ix = (int)((px - lx) * sx); ix = ix < 0 ? 0 : (ix > 31 ? 31 : ix);
    int iy = (int)((py - ly) * sy); iy = iy < 0 ? 0 : (iy > 31 ? 31 : iy);
    return part1by1((unsigned)ix) | (part1by1((unsigned)iy) << 1);
}

// Bucket N points into NCg chunks of 16 (Morton-cell counting sort).
// All 256 threads participate. PT[slot] = {x, y, md=1e10, bits(0xFFFFFFFF-idx)}.
template<int N, int NCg>
__device__ void build_chunks(const float2* __restrict__ src,
                             float4* PT, uint4* CB, float4* BBX,
                             unsigned* HIST, float* red,
                             int tid, int lane, int wv)
{
    // ---- global bbox (containment only; tightness not correctness-critical)
    float lx = 1e30f, hx = -1e30f, ly = 1e30f, hy = -1e30f;
    for (int i = tid; i < N; i += 256) {
        float2 q = src[i];
        lx = fminf(lx, q.x); hx = fmaxf(hx, q.x);
        ly = fminf(ly, q.y); hy = fmaxf(hy, q.y);
    }
#pragma unroll
    for (int d = 1; d < 64; d <<= 1) {
        lx = fminf(lx, __shfl_xor(lx, d)); hx = fmaxf(hx, __shfl_xor(hx, d));
        ly = fminf(ly, __shfl_xor(ly, d)); hy = fmaxf(hy, __shfl_xor(hy, d));
    }
    if (lane == 0) {
        red[wv * 4 + 0] = lx; red[wv * 4 + 1] = hx;
        red[wv * 4 + 2] = ly; red[wv * 4 + 3] = hy;
    }
    __syncthreads();
    lx = fminf(fminf(red[0], red[4]),  fminf(red[8],  red[12]));
    hx = fmaxf(fmaxf(red[1], red[5]),  fmaxf(red[9],  red[13]));
    ly = fminf(fminf(red[2], red[6]),  fminf(red[10], red[14]));
    hy = fmaxf(fmaxf(red[3], red[7]),  fmaxf(red[11], red[15]));
    float sx = 31.999f / fmaxf(hx - lx, 1e-20f);
    float sy = 31.999f / fmaxf(hy - ly, 1e-20f);

    // ---- histogram over 1024 Morton cells
    for (int i = tid; i < 1024; i += 256) HIST[i] = 0u;
    __syncthreads();
    for (int i = tid; i < N; i += 256) {
        float2 q = src[i];
        atomicAdd(&HIST[mortcid(q.x, q.y, lx, ly, sx, sy)], 1u);
    }
    __syncthreads();

    // ---- exclusive prefix (thread t owns bins 4t..4t+3)
    unsigned b0 = HIST[4 * tid], b1 = HIST[4 * tid + 1],
             b2 = HIST[4 * tid + 2], b3 = HIST[4 * tid + 3];
    unsigned s = b0 + b1 + b2 + b3;
    unsigned incl = s;
#pragma unroll
    for (int d = 1; d < 64; d <<= 1) {
        unsigned o = __shfl_up(incl, d);
        if (lane >= d) incl += o;
    }
    if (lane == 63) ((unsigned*)red)[wv] = incl;
    __syncthreads();
    unsigned woff = 0;
    for (int w = 0; w < wv; ++w) woff += ((unsigned*)red)[w];
    unsigned e = woff + incl - s;
    HIST[4 * tid]     = e;
    HIST[4 * tid + 1] = e + b0;
    HIST[4 * tid + 2] = e + b0 + b1;
    HIST[4 * tid + 3] = e + b0 + b1 + b2;
    __syncthreads();

    // ---- scatter (HIST doubles as cursor); slot order within a cell is
    //      nondeterministic but result-invariant (see invariants above).
    for (int i = tid; i < N; i += 256) {
        float2 q = src[i];
        unsigned slot = atomicAdd(&HIST[mortcid(q.x, q.y, lx, ly, sx, sy)], 1u);
        PT[slot] = make_float4(q.x, q.y, 1e10f,
                               __uint_as_float(0xFFFFFFFFu - (unsigned)i));
    }
    __syncthreads();

    // ---- per-chunk bbox + best init (+inf md forces full first-round rescan)
    for (int ci = tid; ci < NCg; ci += 256) {
        float x0 = 1e30f, x1 = -1e30f, y0 = 1e30f, y1 = -1e30f;
#pragma unroll
        for (int j = 0; j < 16; ++j) {
            float4 q = PT[ci * 16 + j];
            x0 = fminf(x0, q.x); x1 = fmaxf(x1, q.x);
            y0 = fminf(y0, q.y); y1 = fmaxf(y1, q.y);
        }
        BBX[ci] = make_float4(x0, y0, x1, y1);
        CB[ci] = make_uint4(0u, 0x7F800000u, 0u, 0u);
    }
    __syncthreads();
}

// Round loop: single wave (wave 0), no barriers. centl[0] must hold c0.
template<int M, int NCg>
__device__ void fps_rounds(float4* __restrict__ PT, uint4* __restrict__ CB,
                           const float4* __restrict__ BBX,
                           float2* __restrict__ centl, int lane)
{
#pragma clang fp contract(off)
    constexpr int K = NCg / 64;
    float4 bb[K];
    uint4 cbc[K];                       // cached chunk bests (valid post-rescan)
#pragma unroll
    for (int k = 0; k < K; ++k) {
        bb[k] = BBX[k * 64 + lane];
        cbc[k] = make_uint4(0u, 0x7F800000u, 0u, 0u);
    }
    float2 c0 = centl[0];
    float cx = c0.x, cy = c0.y;
    int g4 = lane >> 4, l16 = lane & 15;

    for (int it = 1; it < M; ++it) {
#pragma unroll
        for (int k = 0; k < K; ++k) {
            // ---- bound test: rn-monotone => bd2 <= d2(p,c) for all members
            float bmd = __uint_as_float(cbc[k].y);
            float dx = fmaxf(fmaxf(bb[k].x - cx, cx - bb[k].z), 0.0f);
            float dy = fmaxf(fmaxf(bb[k].y - cy, cy - bb[k].w), 0.0f);
            float bd2 = d2_exact(dx, dy);
            unsigned long long mk = __ballot(bd2 < bmd);
            // ---- rescan affected chunks, 4 at a time (16 lanes each)
            while (mk) {
                int n0 = (int)__builtin_ctzll(mk); mk &= mk - 1;
                int n1 = 64, n2 = 64, n3 = 64;
                if (mk) { n1 = (int)__builtin_ctzll(mk); mk &= mk - 1;
                  if (mk) { n2 = (int)__builtin_ctzll(mk); mk &= mk - 1;
                    if (mk) { n3 = (int)__builtin_ctzll(mk); mk &= mk - 1; } } }
                int nb = g4 == 0 ? n0 : (g4 == 1 ? n1 : (g4 == 2 ? n2 : n3));
                if (nb < 64) {                    // group-uniform predicate
                    int cid = k * 64 + nb;
                    int base = cid * 16 + l16;
                    float4 q = PT[base];
                    float d2 = d2_exact(q.x - cx, q.y - cy);
                    float nmd = fminf(q.z, d2);
                    PT[base].z = nmd;
                    unsigned long long key =
                        ((unsigned long long)__float_as_uint(nmd) << 32)
                        | (unsigned long long)__float_as_uint(q.w);
                    float px = q.x, py = q.y;
                    max1p<0x111>(key, px, py);    // 16-lane row reduce -> l16==15
                    max1p<0x112>(key, px, py);
                    max1p<0x114>(key, px, py);
                    max1p<0x118>(key, px, py);
                    if (l16 == 15)
                        CB[cid] = make_uint4((unsigned)key, (unsigned)(key >> 32),
                                             __float_as_uint(px), __float_as_uint(py));
                }
            }
        }
        // ---- global argmax over all chunk bests (coords ride as payload)
        unsigned long long bk = 0ull;
        float bx = 0.0f, by = 0.0f;
#pragma unroll
        for (int k = 0; k < K; ++k) {
            uint4 cb = CB[k * 64 + lane];
            cbc[k] = cb;                          // cache for next round's bound
            unsigned long long kk =
                ((unsigned long long)cb.y << 32) | (unsigned long long)cb.x;
            bool gg = kk > bk;
            bk = gg ? kk : bk;
            bx = gg ? __uint_as_float(cb.z) : bx;
            by = gg ? __uint_as_float(cb.w) : by;
        }
        max1p<0x111>(bk, bx, by); max1p<0x112>(bk, bx, by);
        max1p<0x114>(bk, bx, by); max1p<0x118>(bk, bx, by);
        max1p<0x142>(bk, bx, by); max1p<0x143>(bk, bx, by);   // -> lane 63
        float wx = __uint_as_float((unsigned)__builtin_amdgcn_readlane(
                       (int)__float_as_uint(bx), 63));
        float wy = __uint_as_float((unsigned)__builtin_amdgcn_readlane(
                       (int)__float_as_uint(by), 63));
        if (lane == 0) centl[it] = make_float2(wx, wy);
        cx = wx; cy = wy;
    }
}

// ---------------------------------------------------------------------------
// Fused FPS stage1 (4096 -> 2048) + stage2 (2048 -> 512), lazy-chunked.
// 256 threads: all 4 waves do setup/copies, wave 0 runs the serial rounds
// (waves 1-3 park at the barriers).
// ---------------------------------------------------------------------------
__global__ __launch_bounds__(256, 1) void k_fps_fused(
    const float2* __restrict__ pos, float* __restrict__ p1out,
    float* __restrict__ p2out)
{
    __shared__ float4 PT[NN];            // 64 KB {x,y,md,lo-bits}
    __shared__ uint4  CB[NN / 16];       // 4 KB chunk best {klo,khi,xb,yb}
    __shared__ float4 BBX[NN / 16];      // 4 KB chunk bbox {x0,y0,x1,y1}
    __shared__ unsigned HIST[1024];      // 4 KB sort bins/cursors
    __shared__ float2 C1[M1];            // 16 KB
    __shared__ float2 C2[M2];            // 4 KB
    __shared__ float red[16];            // reduce scratch
    int tid = threadIdx.x, lane = tid & 63, wv = tid >> 6;
    const float2* p = pos + (size_t)blockIdx.x * NN;

    build_chunks<NN, NN / 16>(p, PT, CB, BBX, HIST, red, tid, lane, wv);
    if (tid == 0) C1[0] = p[0];
    __syncthreads();
    if (wv == 0) fps_rounds<M1, NN / 16>(PT, CB, BBX, C1, lane);
    __syncthreads();
    float2* o1 = (float2*)(p1out + (size_t)blockIdx.x * M1 * 2);
    for (int i = tid; i < M1; i += 256) o1[i] = C1[i];

    build_chunks<M1, M1 / 16>((const float2*)C1, PT, CB, BBX, HIST, red, tid, lane, wv);
    if (tid == 0) C2[0] = C1[0];
    __syncthreads();
    if (wv == 0) fps_rounds<M2, M1 / 16>(PT, CB, BBX, C2, lane);
    __syncthreads();
    float2* o2 = (float2*)(p2out + (size_t)blockIdx.x * M2 * 2);
    for (int i = tid; i < M2; i += 256) o2[i] = C2[i];
}

// ---------------------------------------------------------------------------
// Set abstraction: h[i,f] = max_{j: d2(j,i)<=r2} y[j,f]  -  ctr_i @ W_rel.
// ---------------------------------------------------------------------------
__global__ __launch_bounds__(256) void k_sa(
    const float2* __restrict__ candpos, const float* __restrict__ y,
    const float* __restrict__ ctr, const float* __restrict__ W,
    int NP, int F, int relrow, float r2, float* __restrict__ hout)
{
    __shared__ int cnt;
    __shared__ int list[4096];
    int tid = threadIdx.x;
    int b = blockIdx.y;
    size_t crow = (size_t)b * gridDim.x + blockIdx.x;
    if (tid == 0) cnt = 0;
    __syncthreads();
    float cx = ctr[crow * 2], cy = ctr[crow * 2 + 1];
    const float2* cp = candpos + (size_t)b * NP;
    for (int j = tid; j < NP; j += 256) {
        float2 pj = cp[j];
        float d2 = d2_exact(pj.x - cx, pj.y - cy);
        if (d2 <= r2) { int t = atomicAdd(&cnt, 1); list[t] = j; }
    }
    __syncthreads();
    int n = cnt;
    for (int f = tid; f < F; f += 256) {
        float m = -3.0e38f;
        for (int t = 0; t < n; ++t)
            m = fmaxf(m, y[((size_t)b * NP + list[t]) * F + f]);
        float ct = cx * W[(size_t)relrow * F + f] + cy * W[(size_t)(relrow + 1) * F + f];
        hout[crow * F + f] = m - ct;
    }
}

// ---------------------------------------------------------------------------
// y2[j,f] = h1_j @ c2W[0:64] + pos_j @ c2W[64:66] + c2b
// ---------------------------------------------------------------------------
__global__ __launch_bounds__(128) void k_y2(
    const float* __restrict__ h1, const float* __restrict__ p1,
    const float* __restrict__ W, const float* __restrict__ bb,
    float* __restrict__ y2)
{
    __shared__ float sh[64];
    size_t row = blockIdx.x;
    int f = threadIdx.x;
    if (f < 64) sh[f] = h1[row * 64 + f];
    __syncthreads();
    float acc = bb[f] + p1[row * 2] * W[64 * 128 + f]
              + p1[row * 2 + 1] * W[65 * 128 + f];
#pragma unroll
    for (int c = 0; c < 64; ++c) acc += sh[c] * W[c * 128 + f];
    y2[row * 128 + f] = acc;
}

// ---------------------------------------------------------------------------
// g[i,f] = [h2_i, pos_i] @ c3W + c3b; partial max over 8 rows/thread.
// ---------------------------------------------------------------------------
__global__ __launch_bounds__(256) void k_g(
    const float* __restrict__ h2, const float* __restrict__ p2,
    const float* __restrict__ W3, const float* __restrict__ b3,
    float* __restrict__ part)
{
    int f = blockIdx.x * 256 + threadIdx.x;
    int b = blockIdx.z;
    int i0 = blockIdx.y * 8;
    float acc[8];
    float bbv = b3[f];
#pragma unroll
    for (int ii = 0; ii < 8; ++ii) acc[ii] = bbv;
    const float* hrow = h2 + ((size_t)b * M2 + i0) * 128;
    for (int c = 0; c < 128; ++c) {
        float w = W3[(size_t)c * 1024 + f];
#pragma unroll
        for (int ii = 0; ii < 8; ++ii) acc[ii] += hrow[ii * 128 + c] * w;
    }
    float wx = W3[(size_t)128 * 1024 + f];
    float wy = W3[(size_t)129 * 1024 + f];
    const float* prow = p2 + ((size_t)b * M2 + i0) * 2;
    float m = -3.0e38f;
#pragma unroll
    for (int ii = 0; ii < 8; ++ii) {
        float g = acc[ii] + prow[ii * 2] * wx + prow[ii * 2 + 1] * wy;
        m = fmaxf(m, g);
    }
    part[((size_t)b * 64 + blockIdx.y) * 1024 + f] = m;
}

__global__ __launch_bounds__(256) void k_gmax(const float* __restrict__ part,
                                              float* __restrict__ outg)
{
    int f = blockIdx.x * 256 + threadIdx.x;   // 0..4095
    int b = f >> 10, fl = f & 1023;
    float m = -3.0e38f;
#pragma unroll 8
    for (int ig = 0; ig < 64; ++ig)
        m = fmaxf(m, part[((size_t)b * 64 + ig) * 1024 + fl]);
    outg[f] = m;
}

extern "C" void kernel_launch(void* const* d_in, const int* in_sizes, int n_in,
                              void* d_out, int out_size, void* d_ws, size_t ws_size,
                              hipStream_t stream)
{
    const float* x    = (const float*)d_in[0];
    const float* zon  = (const float*)d_in[1];
    const float* lfW1 = (const float*)d_in[2];
    const float* lfb1 = (const float*)d_in[3];
    const float* lfW2 = (const float*)d_in[4];
    const float* lfb2 = (const float*)d_in[5];
    const float* c1W  = (const float*)d_in[6];
    const float* c1b  = (const float*)d_in[7];
    const float* c2W  = (const float*)d_in[8];
    const float* c2b  = (const float*)d_in[9];
    const float* c3W  = (const float*)d_in[10];
    const float* c3b  = (const float*)d_in[11];
    float* out = (float*)d_out;

    // Workspace (fp32). "big" (4 MB) reused: y1 -> y2 -> part.
    char* w = (char*)d_ws;
    float* big = (float*)w;                    w += (size_t)BB * NN * 64 * 4;   // 4 MB
    float* p1  = (float*)w;                    w += (size_t)BB * M1 * 2 * 4;
    float* h1  = (float*)w;                    w += (size_t)BB * M1 * 64 * 4;   // 2 MB
    float* p2  = (float*)w;                    w += (size_t)BB * M2 * 2 * 4;
    float* h2  = (float*)w;                    w += (size_t)BB * M2 * 128 * 4;  // 1 MB
    float* y1 = big, * y2 = big, * part = big;

    k_lf_y1<<<BB * NN / 4, 256, 0, stream>>>((const float2*)x, zon, lfW1, lfb1,
                                             lfW2, lfb2, c1W, c1b, out, y1);
    k_fps_fused<<<BB, 256, 0, stream>>>((const float2*)x, p1, p2);
    k_sa<<<dim3(M1, BB), 256, 0, stream>>>((const float2*)x, y1, p1, c1W,
                                           NN, 64, 65, 0.25f, h1);
    k_y2<<<BB * M1, 128, 0, stream>>>(h1, p1, c2W, c2b, y2);
    k_sa<<<dim3(M2, BB), 256, 0, stream>>>((const float2*)p1, y2, p2, c2W,
                                           M1, 128, 64, 1.0f, h2);
    k_g<<<dim3(4, 64, BB), 256, 0, stream>>>(h2, p2, c3W, c3b, part);
    k_gmax<<<16, 256, 0, stream>>>(part, out + (size_t)BB * NN * 64);
}